// Round 11
// baseline (101.140 us; speedup 1.0000x reference)
//
#include <hip/hip_runtime.h>
#include <stdint.h>

#define DIM     128
#define NMEM    16384
#define NQ_TOT  2048
#define TQ      128                   // queries per WG (2 q-tiles per wave)
#define TN      32                    // mem rows per iter
#define NTILES_TOT (NMEM / TN)        // 512
#define QROWS   (NQ_TOT / TQ)         // 16
#define SHIFT   30.0f
#define PSTR    40                    // Ps^T row stride (shorts): 80B = 5*16B

typedef short    s8v __attribute__((ext_vector_type(8)));
typedef _Float16 h8v __attribute__((ext_vector_type(8)));
typedef float    f4v __attribute__((ext_vector_type(4)));

// ---- workspace layout (bytes) ----
#define OFF_MF16  0u
#define OFF_MHIT  (4u << 20)
#define OFF_NUM   (8u << 20)
#define NUM_BYTES(c)  ((uint32_t)(c) * NQ_TOT * DIM * 2u)   // bf16 partials
#define OFF_DEN(c)    (OFF_NUM + NUM_BYTES(c))
#define WS_NEED(c)    ((size_t)(OFF_DEN(c) + (uint32_t)(c) * NQ_TOT * 4u))

__device__ __forceinline__ uint16_t f2bf(float x) {
    uint32_t u = __float_as_uint(x);
    uint32_t r = u + 0x7fffu + ((u >> 16) & 1u);   // RNE
    return (uint16_t)(r >> 16);
}
__device__ __forceinline__ float bf2f(uint16_t h) {
    return __uint_as_float(((uint32_t)h) << 16);
}
__device__ __forceinline__ uint16_t f2h(float x) {  // fp16 RNE via v_cvt_f16_f32
    union { _Float16 h; uint16_t u; } c;
    c.h = (_Float16)x;
    return c.u;
}

// ==== pre-pass: fp32 memory -> fp16 M (row-major) + bf16 M^T ====
__global__ __launch_bounds__(256)
void convert_kernel(const float* __restrict__ mem, uint16_t* __restrict__ mf16,
                    uint16_t* __restrict__ mhit) {
    __shared__ uint16_t T[DIM * 65];           // [d][n], stride 65 breaks bank conflict
    const int b  = blockIdx.x;                 // 256 blocks x 64 rows
    const int t  = threadIdx.x;
    const int n0 = b * 64;
    #pragma unroll
    for (int k = 0; k < 8; ++k) {
        const int idx4 = t + k * 256;
        const int r    = idx4 >> 5;
        const int c4   = idx4 & 31;
        const float4 v = ((const float4*)(mem + (size_t)(n0 + r) * DIM))[c4];
        *(ushort4*)&mf16[(size_t)(n0 + r) * DIM + c4 * 4] =
            make_ushort4(f2h(v.x), f2h(v.y), f2h(v.z), f2h(v.w));
        T[(c4 * 4 + 0) * 65 + r] = f2bf(v.x);
        T[(c4 * 4 + 1) * 65 + r] = f2bf(v.y);
        T[(c4 * 4 + 2) * 65 + r] = f2bf(v.z);
        T[(c4 * 4 + 3) * 65 + r] = f2bf(v.w);
    }
    __syncthreads();
    #pragma unroll
    for (int p = 0; p < 4; ++p) {
        const int d    = (t >> 3) + p * 32;
        const int part = t & 7;
        uint16_t tmp[8];
        #pragma unroll
        for (int e = 0; e < 8; ++e) tmp[e] = T[d * 65 + part * 8 + e];
        *(uint4*)&mhit[(size_t)d * NMEM + n0 + part * 8] = *(const uint4*)tmp;
    }
}

// ==== main attention: TN=32, swapped QK, q-split PV, ONE barrier/iter ========
// R19 = R18 minus barrier2 (the SINGLE remaining variable of the R17 bisect).
// R18 (dual-barrier + f2bf) PASSED -> TN=32 addressing, q-split PV, epilogue
// all proven. R17 (one-barrier + cvt_pk) failed @66 — an error magnitude only
// possible with num/den INCONSISTENCY (stale/wrong-row Ps reads), since den
// is computed from the same packed w that num consumes. R19 keeps R18's f2bf
// pack + den (proven) and drops ONLY the exp->PV s_barrier, keeping the
// lgkmcnt(0)+sched_barrier fence:
//   pass+faster -> phase overlap real; cvt_pk was R17's bug.
//   pass+same   -> overlap worthless; structure latency-floored.
//   fail        -> barrier2 load-bearing; revert to R15 and declare.
// Sync claim: Ps is wave-private (writes AND reads only rows
// [wv*32,wv*32+32)); own ds_writes drain at lgkmcnt(0) before own ds_reads
// issue (asm memory clobber + sched_barrier(0) pin the order).
template <int NCHK>
__global__ __launch_bounds__(256, 2)
void attn_kernel(const float* __restrict__ query,
                 const uint16_t* __restrict__ mf16,
                 const uint16_t* __restrict__ mhit,
                 uint16_t* __restrict__ num, float* __restrict__ den) {
    // shorts: F0 @0 (4096) | F1 @4096 | T0 @8192 (4096) | T1 @12288 | Ps @16384 (5120)
    __shared__ __align__(16) uint16_t SM[21504];   // 43,008 B
    uint16_t* Ps = SM + 16384;                 // [q128][PSTR] bf16 (P^T: [q][n])

    const int tid   = threadIdx.x;
    const int wv    = tid >> 6;
    const int lane  = tid & 63;
    const int l16   = lane & 15;
    const int quad  = lane >> 4;
    const int bx    = blockIdx.x;
    constexpr int CPX = NCHK / 8;              // chunks pinned per XCD
    const int xcd   = bx & 7;
    const int j     = bx >> 3;
    const int chunk = xcd * CPX + (j % CPX);
    const int qrow  = j / CPX;                 // 0..QROWS-1
    const int q0    = qrow * TQ;
    constexpr int ITERS = NTILES_TOT / NCHK;   // 16 @ NCHK=32
    const int nbase = chunk * (NMEM / NCHK);

    // ---- staging: 16 x 16B global_load_lds per tile, 4 per wave ----
    // F tile: 32 n-rows x 128 d fp16 (8KB, ids 0-7); T: 128 d x 32 n bf16
    // (8KB, ids 8-15). Waves 0,1 -> F; waves 2,3 -> T.
    auto STAGE = [&](int nb, int buf) {
        #pragma unroll
        for (int ii = 0; ii < 4; ++ii) {
            const int id = wv * 4 + ii;
            if (id < 8) {                      // F granule-set
                const int s = id * 64 + lane;  // 0..511
                const int r = s >> 4, c = (s & 15) ^ (r & 7);
                const uint16_t* g = mf16 + (size_t)(nb + r) * DIM + c * 8;
                __builtin_amdgcn_global_load_lds(
                    (const __attribute__((address_space(1))) void*)g,
                    (__attribute__((address_space(3))) void*)&SM[buf * 4096 + id * 512], 16, 0, 0);
            } else {                           // T granule-set
                const int jj = id - 8;
                const int s = jj * 64 + lane;  // 0..511
                const int d = s >> 2, c = (s & 3) ^ (d & 3);
                const uint16_t* g = mhit + (size_t)d * NMEM + nb + c * 8;
                __builtin_amdgcn_global_load_lds(
                    (const __attribute__((address_space(1))) void*)g,
                    (__attribute__((address_space(3))) void*)&SM[8192 + buf * 4096 + jj * 512], 16, 0, 0);
            }
        }
    };
    STAGE(nbase, 0);                           // prologue: tile 0 -> buf 0

    // ---- Q fragments: 2 q-tiles x 4 k-chunks (fp16), q on l16 ----
    h8v qf[2][4];
    #pragma unroll
    for (int qt = 0; qt < 2; ++qt) {
        const float* qp = query + (size_t)(q0 + wv * 32 + qt * 16 + l16) * DIM + quad * 8;
        #pragma unroll
        for (int ks = 0; ks < 4; ++ks) {
            const float4 a = *(const float4*)(qp + ks * 32);
            const float4 b = *(const float4*)(qp + ks * 32 + 4);
            h8v vh;
            vh[0] = (_Float16)a.x; vh[1] = (_Float16)a.y;
            vh[2] = (_Float16)a.z; vh[3] = (_Float16)a.w;
            vh[4] = (_Float16)b.x; vh[5] = (_Float16)b.y;
            vh[6] = (_Float16)b.z; vh[7] = (_Float16)b.w;
            qf[qt][ks] = vh;
        }
    }

    f4v oacc[2][8];                            // O[q = wv*32+qt*16+quad*4+rg][d = dt*16+l16]
    float dacc[2] = {0.f, 0.f};
    #pragma unroll
    for (int qt = 0; qt < 2; ++qt)
        #pragma unroll
        for (int dt = 0; dt < 8; ++dt)
            oacc[qt][dt] = (f4v){0.f, 0.f, 0.f, 0.f};

    for (int it = 0; it < ITERS; ++it) {
        // buf[cur] fully staged (own loads drained, barrier covers the rest);
        // lgkmcnt(0) drains own prev-iter PV ds_reads before Ps rewrite.
        asm volatile("s_waitcnt vmcnt(0) lgkmcnt(0)" ::: "memory");
        __builtin_amdgcn_s_barrier();
        __builtin_amdgcn_sched_barrier(0);
        const int cur = it & 1;
        if (it + 1 < ITERS) STAGE(nbase + (it + 1) * TN, cur ^ 1);

        // ---- QK^T swapped: sacc = S^T, q on l16; 2 n-subtiles ----
        const uint16_t* F = SM + cur * 4096;
        f4v sacc[2][2];
        #pragma unroll
        for (int qt = 0; qt < 2; ++qt)
            #pragma unroll
            for (int nt = 0; nt < 2; ++nt)
                sacc[qt][nt] = (f4v){0.f, 0.f, 0.f, 0.f};
        #pragma unroll
        for (int nt = 0; nt < 2; ++nt) {
            const int r   = nt * 16 + l16;     // A-row = mem row (lane l16)
            const int rsw = r & 7;
            #pragma unroll
            for (int ks = 0; ks < 4; ++ks) {
                const int c = ks * 4 + quad;
                const h8v bm = *(const h8v*)&F[r * DIM + ((c ^ rsw) << 3)];
                #pragma unroll
                for (int qt = 0; qt < 2; ++qt)
                    sacc[qt][nt] = __builtin_amdgcn_mfma_f32_16x16x32_f16(bm, qf[qt][ks], sacc[qt][nt], 0, 0, 0);
            }
        }

        // ---- exp + f2bf pack (proven path) + OWN-row Ps write ----
        #pragma unroll
        for (int qt = 0; qt < 2; ++qt) {
            const int qloc = wv * 32 + qt * 16 + l16;
            #pragma unroll
            for (int nt = 0; nt < 2; ++nt) {
                const uint16_t pb0 = f2bf(__expf(sacc[qt][nt][0] - SHIFT));
                const uint16_t pb1 = f2bf(__expf(sacc[qt][nt][1] - SHIFT));
                const uint16_t pb2 = f2bf(__expf(sacc[qt][nt][2] - SHIFT));
                const uint16_t pb3 = f2bf(__expf(sacc[qt][nt][3] - SHIFT));
                dacc[qt] += (bf2f(pb0) + bf2f(pb1)) + (bf2f(pb2) + bf2f(pb3));
                uint2 w;
                w.x = (uint32_t)pb0 | ((uint32_t)pb1 << 16);
                w.y = (uint32_t)pb2 | ((uint32_t)pb3 << 16);
                // Ps[q][n = nt*16 + quad*4 + {0..3}] = P[n][q]
                *(uint2*)&Ps[qloc * PSTR + nt * 16 + quad * 4] = w;
            }
        }

        // ---- R19 delta: NO s_barrier here. Own writes drained before own
        // reads; Ps is wave-private (write range == read range == own rows).
        asm volatile("s_waitcnt lgkmcnt(0)" ::: "memory");
        __builtin_amdgcn_sched_barrier(0);

        // ---- PV q-split: wave owns q in [wv*32,wv*32+32), all 128 d; K=32 ----
        s8v pf[2];
        #pragma unroll
        for (int qt = 0; qt < 2; ++qt)
            pf[qt] = *(const s8v*)&Ps[(wv * 32 + qt * 16 + l16) * PSTR + quad * 8];
        const uint16_t* T = SM + 8192 + cur * 4096;
        #pragma unroll
        for (int dt = 0; dt < 8; ++dt) {
            const int d  = dt * 16 + l16;
            const s8v bt = *(const s8v*)&T[d * TN + ((quad ^ (d & 3)) << 3)];
            #pragma unroll
            for (int qt = 0; qt < 2; ++qt)
                oacc[qt][dt] = __builtin_amdgcn_mfma_f32_16x16x32_bf16(pf[qt], bt, oacc[qt][dt], 0, 0, 0);
        }
    }

    // ---- denominator: q = l16; sum the 4 quads' disjoint n-sets ----
    #pragma unroll
    for (int qt = 0; qt < 2; ++qt) {
        dacc[qt] += __shfl_xor(dacc[qt], 16, 64);
        dacc[qt] += __shfl_xor(dacc[qt], 32, 64);
    }
    __syncthreads();                           // all LDS reads + tail DMA done; SM reusable
    if (quad == 0) {
        #pragma unroll
        for (int qt = 0; qt < 2; ++qt)
            den[chunk * NQ_TOT + q0 + wv * 32 + qt * 16 + l16] = dacc[qt];
    }
    // ---- O merge into LDS (bf16) for coalesced stores ----
    uint16_t* Obuf = SM;                       // 128 q x 128 d x 2B = 32 KB (fits 43K)
    #pragma unroll
    for (int qt = 0; qt < 2; ++qt)
        #pragma unroll
        for (int dt = 0; dt < 8; ++dt)
            #pragma unroll
            for (int rg = 0; rg < 4; ++rg) {
                const int qq = wv * 32 + qt * 16 + quad * 4 + rg;
                const int dd = dt * 16 + l16;
                Obuf[qq * DIM + dd] = f2bf(oacc[qt][dt][rg]);
            }
    __syncthreads();
    {
        uint4* dst = (uint4*)(num + ((size_t)chunk * NQ_TOT + q0) * DIM);
        const uint4* src = (const uint4*)Obuf;
        #pragma unroll
        for (int k = 0; k < 8; ++k) {
            const int f = tid + k * 256;       // 2048 uint4s (32 KB)
            dst[f] = src[f];
        }
    }
}

// ============ final reduce over chunks + normalize ============
template <int NCHK>
__global__ __launch_bounds__(256)
void reduce_kernel(const uint16_t* __restrict__ num, const float* __restrict__ den,
                   float* __restrict__ out) {
    const int f = blockIdx.x * 256 + threadIdx.x;   // 65536 groups of 4
    const int q = f >> 5;
    float4 ns = make_float4(0.f, 0.f, 0.f, 0.f);
    float ds = 0.f;
    #pragma unroll
    for (int c = 0; c < NCHK; ++c) {
        const ushort4 v = ((const ushort4*)num)[c * (NQ_TOT * DIM / 4) + f];
        ns.x += bf2f(v.x); ns.y += bf2f(v.y); ns.z += bf2f(v.z); ns.w += bf2f(v.w);
        ds += den[c * NQ_TOT + q];
    }
    const float inv = 1.0f / ds;
    ((float4*)out)[f] = make_float4(ns.x * inv, ns.y * inv, ns.z * inv, ns.w * inv);
}

// ============ fallback (round-1 fp32 kernel) if ws too small ============
#define FTQ 8
#define FTN 64
#define FNTILES (NMEM / FTN)
#define FBLOCK 512
#define MPAD 132
#define PPAD 68

__global__ __launch_bounds__(FBLOCK, 2)
void sparse_attn_fp32(const float* __restrict__ query,
                      const float* __restrict__ memory,
                      float* __restrict__ out) {
    __shared__ float Qs[FTQ * MPAD];
    __shared__ float Ms[FTN * MPAD];
    __shared__ float Psh[FTQ * PPAD];
    __shared__ float Rd[FTQ * PPAD];
    const int tid = threadIdx.x;
    const int q = tid & 7, rest = tid >> 3;
    const int ng = rest, dg = rest & 31, half = rest >> 5;
    const long q0 = (long)blockIdx.x * FTQ;
    if (tid < FTQ * DIM / 4) {
        const float4 v = ((const float4*)(query + q0 * DIM))[tid];
        *(float4*)&Qs[(tid >> 5) * MPAD + ((tid & 31) << 2)] = v;
    }
    float4 pf[4];
    {
        const float4* msrc = (const float4*)memory;
        #pragma unroll
        for (int k = 0; k < 4; ++k) pf[k] = msrc[tid + k * FBLOCK];
    }
    float4 acc = make_float4(0.f, 0.f, 0.f, 0.f);
    float l_part = 0.f;
    for (int t = 0; t < FNTILES; ++t) {
        __syncthreads();
        #pragma unroll
        for (int k = 0; k < 4; ++k) {
            const int f4 = tid + k * FBLOCK;
            *(float4*)&Ms[(f4 >> 5) * MPAD + ((f4 & 31) << 2)] = pf[k];
        }
        __syncthreads();
        if (t + 1 < FNTILES) {
            const float4* msrc = (const float4*)(memory + (long)(t + 1) * FTN * DIM);
            #pragma unroll
            for (int k = 0; k < 4; ++k) pf[k] = msrc[tid + k * FBLOCK];
        }
        float4 s4 = make_float4(0.f, 0.f, 0.f, 0.f);
        const float* qrow = &Qs[q * MPAD];
        const float* mrow = &Ms[ng * MPAD];
        #pragma unroll
        for (int jj = 0; jj < 32; ++jj) {
            const float4 qv = *(const float4*)&qrow[jj * 4];
            const float4 mv = *(const float4*)&mrow[jj * 4];
            s4.x += qv.x * mv.x; s4.y += qv.y * mv.y;
            s4.z += qv.z * mv.z; s4.w += qv.w * mv.w;
        }
        const float p = __expf(((s4.x + s4.y) + (s4.z + s4.w)) - SHIFT);
        Psh[q * PPAD + ng] = p;
        l_part += p;
        __syncthreads();
        #pragma unroll
        for (int n = 0; n < 32; ++n) {
            const int nn = half * 32 + n;
            const float pw = Psh[q * PPAD + nn];
            const float4 mv = *(const float4*)&Ms[nn * MPAD + dg * 4];
            acc.x += pw * mv.x; acc.y += pw * mv.y;
            acc.z += pw * mv.z; acc.w += pw * mv.w;
        }
    }
    __syncthreads();
    Rd[q * PPAD + rest] = l_part;
    if (half == 1) *(float4*)&Ms[q * MPAD + dg * 4] = acc;
    __syncthreads();
    if (half == 0) {
        const float4 o2 = *(const float4*)&Ms[q * MPAD + dg * 4];
        float l = 0.f;
        #pragma unroll 8
        for (int i = 0; i < 64; ++i) l += Rd[q * PPAD + i];
        const float inv = 1.0f / l;
        float4 o;
        o.x = (acc.x + o2.x) * inv; o.y = (acc.y + o2.y) * inv;
        o.z = (acc.z + o2.z) * inv; o.w = (acc.w + o2.w) * inv;
        *(float4*)(out + (q0 + q) * DIM + dg * 4) = o;
    }
}

extern "C" void kernel_launch(void* const* d_in, const int* in_sizes, int n_in,
                              void* d_out, int out_size, void* d_ws, size_t ws_size,
                              hipStream_t stream) {
    const float* query  = (const float*)d_in[0];
    const float* memory = (const float*)d_in[1];
    float* out = (float*)d_out;
    if (ws_size >= WS_NEED(16)) {
        uint16_t* mf16 = (uint16_t*)((char*)d_ws + OFF_MF16);
        uint16_t* mhit = (uint16_t*)((char*)d_ws + OFF_MHIT);
        uint16_t* num  = (uint16_t*)((char*)d_ws + OFF_NUM);
        convert_kernel<<<NMEM / 64, 256, 0, stream>>>(memory, mf16, mhit);
        if (ws_size >= WS_NEED(32)) {
            float* den = (float*)((char*)d_ws + OFF_DEN(32));
            attn_kernel<32><<<QROWS * 32, 256, 0, stream>>>(query, mf16, mhit, num, den);
            reduce_kernel<32><<<NQ_TOT * DIM / 4 / 256, 256, 0, stream>>>(num, den, out);
        } else {
            float* den = (float*)((char*)d_ws + OFF_DEN(16));
            attn_kernel<16><<<QROWS * 16, 256, 0, stream>>>(query, mf16, mhit, num, den);
            reduce_kernel<16><<<NQ_TOT * DIM / 4 / 256, 256, 0, stream>>>(num, den, out);
        }
    } else {
        sparse_attn_fp32<<<NQ_TOT / FTQ, FBLOCK, 0, stream>>>(query, memory, out);
    }
}

// Round 12
// 98.627 us; speedup vs baseline: 1.0255x; 1.0255x over previous
//
#include <hip/hip_runtime.h>
#include <stdint.h>

#define DIM     128
#define NMEM    16384
#define NQ_TOT  2048
#define TQ      128                   // queries per WG (2 q-tiles per wave)
#define TN      64                    // mem rows per iter
#define NTILES_TOT (NMEM / TN)        // 256
#define QROWS   (NQ_TOT / TQ)         // 16
#define SHIFT   30.0f

typedef short    s8v __attribute__((ext_vector_type(8)));
typedef _Float16 h8v __attribute__((ext_vector_type(8)));
typedef float    f4v __attribute__((ext_vector_type(4)));

// ---- workspace layout (bytes) ----
#define OFF_MF16  0u
#define OFF_MHIT  (4u << 20)
#define OFF_NUM   (8u << 20)
#define NUM_BYTES(c)  ((uint32_t)(c) * NQ_TOT * DIM * 2u)   // bf16 partials
#define OFF_DEN(c)    (OFF_NUM + NUM_BYTES(c))
#define WS_NEED(c)    ((size_t)(OFF_DEN(c) + (uint32_t)(c) * NQ_TOT * 4u))

__device__ __forceinline__ uint16_t f2bf(float x) {
    uint32_t u = __float_as_uint(x);
    uint32_t r = u + 0x7fffu + ((u >> 16) & 1u);   // RNE
    return (uint16_t)(r >> 16);
}
__device__ __forceinline__ float bf2f(uint16_t h) {
    return __uint_as_float(((uint32_t)h) << 16);
}
__device__ __forceinline__ uint16_t f2h(float x) {  // fp16 RNE via v_cvt_f16_f32
    union { _Float16 h; uint16_t u; } c;
    c.h = (_Float16)x;
    return c.u;
}

// ==== pre-pass: fp32 memory -> fp16 M (row-major) + bf16 M^T ====
__global__ __launch_bounds__(256)
void convert_kernel(const float* __restrict__ mem, uint16_t* __restrict__ mf16,
                    uint16_t* __restrict__ mhit) {
    __shared__ uint16_t T[DIM * 65];           // [d][n], stride 65 breaks bank conflict
    const int b  = blockIdx.x;                 // 256 blocks x 64 rows
    const int t  = threadIdx.x;
    const int n0 = b * 64;
    #pragma unroll
    for (int k = 0; k < 8; ++k) {
        const int idx4 = t + k * 256;
        const int r    = idx4 >> 5;
        const int c4   = idx4 & 31;
        const float4 v = ((const float4*)(mem + (size_t)(n0 + r) * DIM))[c4];
        *(ushort4*)&mf16[(size_t)(n0 + r) * DIM + c4 * 4] =
            make_ushort4(f2h(v.x), f2h(v.y), f2h(v.z), f2h(v.w));
        T[(c4 * 4 + 0) * 65 + r] = f2bf(v.x);
        T[(c4 * 4 + 1) * 65 + r] = f2bf(v.y);
        T[(c4 * 4 + 2) * 65 + r] = f2bf(v.z);
        T[(c4 * 4 + 3) * 65 + r] = f2bf(v.w);
    }
    __syncthreads();
    #pragma unroll
    for (int p = 0; p < 4; ++p) {
        const int d    = (t >> 3) + p * 32;
        const int part = t & 7;
        uint16_t tmp[8];
        #pragma unroll
        for (int e = 0; e < 8; ++e) tmp[e] = T[d * 65 + part * 8 + e];
        *(uint4*)&mhit[(size_t)d * NMEM + n0 + part * 8] = *(const uint4*)tmp;
    }
}

// ==== main attention: TN=64, swapped QK, IN-REGISTER P repack, no Ps LDS =====
// R20: the bisect (R15/R17/R18/R19) convicted cvtpk_bf16 inline asm as the
// sole bug behind R12-R14/R17 (every failure used it; every pass used f2bf).
// This resurrects R14's permlane repack with f2bf-packed inputs:
//   per (qt,ksP): A0,A1 = packed words of nt=2ksP; B0,B1 = of nt=2ksP+1.
//   swap32(A,B) then swap16(A,B):
//     swap32: D[32..63] <-> S[0..31] (odd 32-row of D <-> even of S)
//     swap16: D[16..31] <-> S[0..15], D[48..63] <-> S[32..47]
//   -> A'' = P[q=l16][n=32ksP+8quad+{0,1}] (+A1'' gives {2,3}),
//      B'' = {4,5} (+B1'' {6,7}) — derived & lane-checked at all 4 quads;
//   exactly the A-operand fragment R18's (PASSING) LDS-path pf read produced.
// Ps buffer, its writes/reads, and all intra-iter fences are GONE: the only
// sync is R19's proven top-of-iter vmcnt(0)+lgkmcnt(0)+barrier. F/T double-
// buffered: LDS = 65536 B exactly (<= 64KB static limit; R16's 84KB was over).
// 8 iters; q-split PV (R18-proven); staging/QK/PV-bt formulas R15-proven.
template <int NCHK>
__global__ __launch_bounds__(256, 2)
void attn_kernel(const float* __restrict__ query,
                 const uint16_t* __restrict__ mf16,
                 const uint16_t* __restrict__ mhit,
                 uint16_t* __restrict__ num, float* __restrict__ den) {
    // shorts: F0 @0 | F1 @8192 | T0 @16384 | T1 @24576  -> 65536 B exactly
    __shared__ __align__(16) uint16_t SM[32768];

    const int tid   = threadIdx.x;
    const int wv    = tid >> 6;
    const int lane  = tid & 63;
    const int l16   = lane & 15;
    const int quad  = lane >> 4;
    const int bx    = blockIdx.x;
    constexpr int CPX = NCHK / 8;              // chunks pinned per XCD
    const int xcd   = bx & 7;
    const int j     = bx >> 3;
    const int chunk = xcd * CPX + (j % CPX);
    const int qrow  = j / CPX;                 // 0..QROWS-1
    const int q0    = qrow * TQ;
    constexpr int ITERS = NTILES_TOT / NCHK;   // 8 @ NCHK=32
    const int nbase = chunk * (NMEM / NCHK);

    // ---- staging: 32 x 16B global_load_lds per tile, 8 per wave ----
    auto STAGE = [&](int nb, int buf) {
        #pragma unroll
        for (int ii = 0; ii < 8; ++ii) {
            const int id = wv * 8 + ii;
            if (id < 16) {                     // F: 64 n-rows x 128 d fp16 (16KB)
                const int s = id * 64 + lane;
                const int r = s >> 4, c = (s & 15) ^ (r & 7);
                const uint16_t* g = mf16 + (size_t)(nb + r) * DIM + c * 8;
                __builtin_amdgcn_global_load_lds(
                    (const __attribute__((address_space(1))) void*)g,
                    (__attribute__((address_space(3))) void*)&SM[buf * 8192 + id * 512], 16, 0, 0);
            } else {                           // T: 128 d-rows x 64 n bf16 (16KB)
                const int jj = id - 16;
                const int s = jj * 64 + lane;
                const int d = s >> 3, c = (s & 7) ^ (d & 7);
                const uint16_t* g = mhit + (size_t)d * NMEM + nb + c * 8;
                __builtin_amdgcn_global_load_lds(
                    (const __attribute__((address_space(1))) void*)g,
                    (__attribute__((address_space(3))) void*)&SM[16384 + buf * 8192 + jj * 512], 16, 0, 0);
            }
        }
    };
    STAGE(nbase, 0);                           // prologue: tile 0 -> buf 0

    // ---- Q fragments: 2 q-tiles x 4 k-chunks (fp16), q on l16 ----
    h8v qf[2][4];
    #pragma unroll
    for (int qt = 0; qt < 2; ++qt) {
        const float* qp = query + (size_t)(q0 + wv * 32 + qt * 16 + l16) * DIM + quad * 8;
        #pragma unroll
        for (int ks = 0; ks < 4; ++ks) {
            const float4 a = *(const float4*)(qp + ks * 32);
            const float4 b = *(const float4*)(qp + ks * 32 + 4);
            h8v vh;
            vh[0] = (_Float16)a.x; vh[1] = (_Float16)a.y;
            vh[2] = (_Float16)a.z; vh[3] = (_Float16)a.w;
            vh[4] = (_Float16)b.x; vh[5] = (_Float16)b.y;
            vh[6] = (_Float16)b.z; vh[7] = (_Float16)b.w;
            qf[qt][ks] = vh;
        }
    }

    f4v oacc[2][8];                            // O[q = wv*32+qt*16+quad*4+rg][d = dt*16+l16]
    float dacc[2] = {0.f, 0.f};
    #pragma unroll
    for (int qt = 0; qt < 2; ++qt)
        #pragma unroll
        for (int dt = 0; dt < 8; ++dt)
            oacc[qt][dt] = (f4v){0.f, 0.f, 0.f, 0.f};

    for (int it = 0; it < ITERS; ++it) {
        // buf[cur] fully staged (own loads drained; barrier covers the rest);
        // lgkmcnt(0) drains own prev-iter T/F ds_reads before DMA overwrite.
        asm volatile("s_waitcnt vmcnt(0) lgkmcnt(0)" ::: "memory");
        __builtin_amdgcn_s_barrier();
        __builtin_amdgcn_sched_barrier(0);
        const int cur = it & 1;
        if (it + 1 < ITERS) STAGE(nbase + (it + 1) * TN, cur ^ 1);

        // ---- QK^T swapped (R15-proven): sacc = S^T, q on l16; 4 n-subtiles --
        const uint16_t* F = SM + cur * 8192;
        f4v sacc[2][4];
        #pragma unroll
        for (int qt = 0; qt < 2; ++qt)
            #pragma unroll
            for (int nt = 0; nt < 4; ++nt)
                sacc[qt][nt] = (f4v){0.f, 0.f, 0.f, 0.f};
        #pragma unroll
        for (int nt = 0; nt < 4; ++nt) {
            const int r   = nt * 16 + l16;     // A-row = mem row (lane l16)
            const int rsw = r & 7;
            #pragma unroll
            for (int ks = 0; ks < 4; ++ks) {
                const int c = ks * 4 + quad;
                const h8v bm = *(const h8v*)&F[r * DIM + ((c ^ rsw) << 3)];
                #pragma unroll
                for (int qt = 0; qt < 2; ++qt)
                    sacc[qt][nt] = __builtin_amdgcn_mfma_f32_16x16x32_f16(bm, qf[qt][ks], sacc[qt][nt], 0, 0, 0);
            }
        }

        // ---- exp + f2bf pack (proven) -> W words; den from rounded vals ----
        uint32_t W[2][4][2];
        #pragma unroll
        for (int qt = 0; qt < 2; ++qt)
            #pragma unroll
            for (int nt = 0; nt < 4; ++nt) {
                const uint16_t pb0 = f2bf(__expf(sacc[qt][nt][0] - SHIFT));
                const uint16_t pb1 = f2bf(__expf(sacc[qt][nt][1] - SHIFT));
                const uint16_t pb2 = f2bf(__expf(sacc[qt][nt][2] - SHIFT));
                const uint16_t pb3 = f2bf(__expf(sacc[qt][nt][3] - SHIFT));
                dacc[qt] += (bf2f(pb0) + bf2f(pb1)) + (bf2f(pb2) + bf2f(pb3));
                W[qt][nt][0] = (uint32_t)pb0 | ((uint32_t)pb1 << 16);
                W[qt][nt][1] = (uint32_t)pb2 | ((uint32_t)pb3 << 16);
            }

        // ---- in-register repack: swap32 then swap16 (derived + lane-checked)
        // pa[qt][ksP] lane (l16,quad) = P[q=..l16][n = 32ksP + 8quad + j]
        s8v pa[2][2];
        #pragma unroll
        for (int qt = 0; qt < 2; ++qt)
            #pragma unroll
            for (int ksP = 0; ksP < 2; ++ksP) {
                uint32_t a0 = W[qt][2 * ksP][0];
                uint32_t a1 = W[qt][2 * ksP][1];
                uint32_t b0 = W[qt][2 * ksP + 1][0];
                uint32_t b1 = W[qt][2 * ksP + 1][1];
                asm("v_permlane32_swap_b32 %0, %1" : "+v"(a0), "+v"(b0));
                asm("v_permlane32_swap_b32 %0, %1" : "+v"(a1), "+v"(b1));
                asm("v_permlane16_swap_b32 %0, %1" : "+v"(a0), "+v"(b0));
                asm("v_permlane16_swap_b32 %0, %1" : "+v"(a1), "+v"(b1));
                union { uint32_t d[4]; s8v v8; } P;
                P.d[0] = a0;                   // n = 8quad + {0,1}
                P.d[1] = a1;                   // n = 8quad + {2,3}
                P.d[2] = b0;                   // n = 8quad + {4,5}
                P.d[3] = b1;                   // n = 8quad + {6,7}
                pa[qt][ksP] = P.v8;
            }

        // ---- PV q-split (R18-proven orient): A = pa (reg), B = V^T from LDS -
        const uint16_t* T = SM + 16384 + cur * 8192;
        #pragma unroll
        for (int dt = 0; dt < 8; ++dt) {
            const int d   = dt * 16 + l16;
            const int dsw = d & 7;
            const s8v bt0 = *(const s8v*)&T[d * TN + (((0 * 4 + quad) ^ dsw) << 3)];
            const s8v bt1 = *(const s8v*)&T[d * TN + (((1 * 4 + quad) ^ dsw) << 3)];
            #pragma unroll
            for (int qt = 0; qt < 2; ++qt) {
                oacc[qt][dt] = __builtin_amdgcn_mfma_f32_16x16x32_bf16(pa[qt][0], bt0, oacc[qt][dt], 0, 0, 0);
                oacc[qt][dt] = __builtin_amdgcn_mfma_f32_16x16x32_bf16(pa[qt][1], bt1, oacc[qt][dt], 0, 0, 0);
            }
        }
    }

    // ---- denominator: q = l16; sum the 4 quads' disjoint n-sets ----
    #pragma unroll
    for (int qt = 0; qt < 2; ++qt) {
        dacc[qt] += __shfl_xor(dacc[qt], 16, 64);
        dacc[qt] += __shfl_xor(dacc[qt], 32, 64);
    }
    __syncthreads();                           // all LDS reads done; SM reusable
    if (quad == 0) {
        #pragma unroll
        for (int qt = 0; qt < 2; ++qt)
            den[chunk * NQ_TOT + q0 + wv * 32 + qt * 16 + l16] = dacc[qt];
    }
    // ---- O merge into LDS (bf16) for coalesced stores (R18-proven) ----
    uint16_t* Obuf = SM;                       // 128 q x 128 d x 2B = 32 KB
    #pragma unroll
    for (int qt = 0; qt < 2; ++qt)
        #pragma unroll
        for (int dt = 0; dt < 8; ++dt)
            #pragma unroll
            for (int rg = 0; rg < 4; ++rg) {
                const int qq = wv * 32 + qt * 16 + quad * 4 + rg;
                const int dd = dt * 16 + l16;
                Obuf[qq * DIM + dd] = f2bf(oacc[qt][dt][rg]);
            }
    __syncthreads();
    {
        uint4* dst = (uint4*)(num + ((size_t)chunk * NQ_TOT + q0) * DIM);
        const uint4* src = (const uint4*)Obuf;
        #pragma unroll
        for (int k = 0; k < 8; ++k) {
            const int f = tid + k * 256;       // 2048 uint4s (32 KB)
            dst[f] = src[f];
        }
    }
}

// ============ final reduce over chunks + normalize ============
template <int NCHK>
__global__ __launch_bounds__(256)
void reduce_kernel(const uint16_t* __restrict__ num, const float* __restrict__ den,
                   float* __restrict__ out) {
    const int f = blockIdx.x * 256 + threadIdx.x;   // 65536 groups of 4
    const int q = f >> 5;
    float4 ns = make_float4(0.f, 0.f, 0.f, 0.f);
    float ds = 0.f;
    #pragma unroll
    for (int c = 0; c < NCHK; ++c) {
        const ushort4 v = ((const ushort4*)num)[c * (NQ_TOT * DIM / 4) + f];
        ns.x += bf2f(v.x); ns.y += bf2f(v.y); ns.z += bf2f(v.z); ns.w += bf2f(v.w);
        ds += den[c * NQ_TOT + q];
    }
    const float inv = 1.0f / ds;
    ((float4*)out)[f] = make_float4(ns.x * inv, ns.y * inv, ns.z * inv, ns.w * inv);
}

// ============ fallback (round-1 fp32 kernel) if ws too small ============
#define FTQ 8
#define FTN 64
#define FNTILES (NMEM / FTN)
#define FBLOCK 512
#define MPAD 132
#define PPAD 68

__global__ __launch_bounds__(FBLOCK, 2)
void sparse_attn_fp32(const float* __restrict__ query,
                      const float* __restrict__ memory,
                      float* __restrict__ out) {
    __shared__ float Qs[FTQ * MPAD];
    __shared__ float Ms[FTN * MPAD];
    __shared__ float Psh[FTQ * PPAD];
    __shared__ float Rd[FTQ * PPAD];
    const int tid = threadIdx.x;
    const int q = tid & 7, rest = tid >> 3;
    const int ng = rest, dg = rest & 31, half = rest >> 5;
    const long q0 = (long)blockIdx.x * FTQ;
    if (tid < FTQ * DIM / 4) {
        const float4 v = ((const float4*)(query + q0 * DIM))[tid];
        *(float4*)&Qs[(tid >> 5) * MPAD + ((tid & 31) << 2)] = v;
    }
    float4 pf[4];
    {
        const float4* msrc = (const float4*)memory;
        #pragma unroll
        for (int k = 0; k < 4; ++k) pf[k] = msrc[tid + k * FBLOCK];
    }
    float4 acc = make_float4(0.f, 0.f, 0.f, 0.f);
    float l_part = 0.f;
    for (int t = 0; t < FNTILES; ++t) {
        __syncthreads();
        #pragma unroll
        for (int k = 0; k < 4; ++k) {
            const int f4 = tid + k * FBLOCK;
            *(float4*)&Ms[(f4 >> 5) * MPAD + ((f4 & 31) << 2)] = pf[k];
        }
        __syncthreads();
        if (t + 1 < FNTILES) {
            const float4* msrc = (const float4*)(memory + (long)(t + 1) * FTN * DIM);
            #pragma unroll
            for (int k = 0; k < 4; ++k) pf[k] = msrc[tid + k * FBLOCK];
        }
        float4 s4 = make_float4(0.f, 0.f, 0.f, 0.f);
        const float* qrow = &Qs[q * MPAD];
        const float* mrow = &Ms[ng * MPAD];
        #pragma unroll
        for (int jj = 0; jj < 32; ++jj) {
            const float4 qv = *(const float4*)&qrow[jj * 4];
            const float4 mv = *(const float4*)&mrow[jj * 4];
            s4.x += qv.x * mv.x; s4.y += qv.y * mv.y;
            s4.z += qv.z * mv.z; s4.w += qv.w * mv.w;
        }
        const float p = __expf(((s4.x + s4.y) + (s4.z + s4.w)) - SHIFT);
        Psh[q * PPAD + ng] = p;
        l_part += p;
        __syncthreads();
        #pragma unroll
        for (int n = 0; n < 32; ++n) {
            const int nn = half * 32 + n;
            const float pw = Psh[q * PPAD + nn];
            const float4 mv = *(const float4*)&Ms[nn * MPAD + dg * 4];
            acc.x += pw * mv.x; acc.y += pw * mv.y;
            acc.z += pw * mv.z; acc.w += pw * mv.w;
        }
    }
    __syncthreads();
    Rd[q * PPAD + rest] = l_part;
    if (half == 1) *(float4*)&Ms[q * MPAD + dg * 4] = acc;
    __syncthreads();
    if (half == 0) {
        const float4 o2 = *(const float4*)&Ms[q * MPAD + dg * 4];
        float l = 0.f;
        #pragma unroll 8
        for (int i = 0; i < 64; ++i) l += Rd[q * PPAD + i];
        const float inv = 1.0f / l;
        float4 o;
        o.x = (acc.x + o2.x) * inv; o.y = (acc.y + o2.y) * inv;
        o.z = (acc.z + o2.z) * inv; o.w = (acc.w + o2.w) * inv;
        *(float4*)(out + (q0 + q) * DIM + dg * 4) = o;
    }
}

extern "C" void kernel_launch(void* const* d_in, const int* in_sizes, int n_in,
                              void* d_out, int out_size, void* d_ws, size_t ws_size,
                              hipStream_t stream) {
    const float* query  = (const float*)d_in[0];
    const float* memory = (const float*)d_in[1];
    float* out = (float*)d_out;
    if (ws_size >= WS_NEED(16)) {
        uint16_t* mf16 = (uint16_t*)((char*)d_ws + OFF_MF16);
        uint16_t* mhit = (uint16_t*)((char*)d_ws + OFF_MHIT);
        uint16_t* num  = (uint16_t*)((char*)d_ws + OFF_NUM);
        convert_kernel<<<NMEM / 64, 256, 0, stream>>>(memory, mf16, mhit);
        if (ws_size >= WS_NEED(32)) {
            float* den = (float*)((char*)d_ws + OFF_DEN(32));
            attn_kernel<32><<<QROWS * 32, 256, 0, stream>>>(query, mf16, mhit, num, den);
            reduce_kernel<32><<<NQ_TOT * DIM / 4 / 256, 256, 0, stream>>>(num, den, out);
        } else {
            float* den = (float*)((char*)d_ws + OFF_DEN(16));
            attn_kernel<16><<<QROWS * 16, 256, 0, stream>>>(query, mf16, mhit, num, den);
            reduce_kernel<16><<<NQ_TOT * DIM / 4 / 256, 256, 0, stream>>>(num, den, out);
        }
    } else {
        sparse_attn_fp32<<<NQ_TOT / FTQ, FBLOCK, 0, stream>>>(query, memory, out);
    }
}